// Round 17
// baseline (609.944 us; speedup 1.0000x reference)
//
#include <hip/hip_runtime.h>
#include <hip/hip_bf16.h>

#define NB 8
#define NSEQ 1024
#define DMODEL 512
#define DF 2048
#define NEXP 8
#define NHEAD 8
#define HDIM 64
#define T_TOK (NB * NSEQ)

typedef unsigned short u16;
typedef float f32x4_t __attribute__((ext_vector_type(4)));
typedef __bf16 bf16x8_t __attribute__((ext_vector_type(8)));

__device__ __forceinline__ u16 f2b(float f) {
  __hip_bfloat16 h = __float2bfloat16(f);
  return *reinterpret_cast<u16*>(&h);
}
__device__ __forceinline__ float b2f(u16 u) {
  return __uint_as_float((unsigned)u << 16);
}
// async global->LDS, 16B per lane; lds ptr must be wave-uniform
__device__ __forceinline__ void gl_lds16(const u16* g, u16* l) {
  __builtin_amdgcn_global_load_lds(
      (const __attribute__((address_space(1))) unsigned int*)g,
      (__attribute__((address_space(3))) unsigned int*)l, 16, 0, 0);
}

// ---------------- elementwise conversions ----------------------------------
__global__ __launch_bounds__(256) void k_cvt_hl(const float* __restrict__ src,
                                                u16* __restrict__ hi,
                                                u16* __restrict__ lo, int n4) {
  const int i = blockIdx.x * 256 + threadIdx.x;
  if (i >= n4) return;
  const float4 v = ((const float4*)src)[i];
  ushort4 h, l;
  h.x = f2b(v.x); l.x = f2b(v.x - b2f(h.x));
  h.y = f2b(v.y); l.y = f2b(v.y - b2f(h.y));
  h.z = f2b(v.z); l.z = f2b(v.z - b2f(h.z));
  h.w = f2b(v.w); l.w = f2b(v.w - b2f(h.w));
  ((ushort4*)hi)[i] = h;
  ((ushort4*)lo)[i] = l;
}

__global__ __launch_bounds__(256) void k_cvt_b(const float* __restrict__ src,
                                               u16* __restrict__ dst, int n4) {
  const int i = blockIdx.x * 256 + threadIdx.x;
  if (i >= n4) return;
  const float4 v = ((const float4*)src)[i];
  ushort4 h;
  h.x = f2b(v.x); h.y = f2b(v.y); h.z = f2b(v.z); h.w = f2b(v.w);
  ((ushort4*)dst)[i] = h;
}

// transpose + split per batch: src [R][C] f32 -> hi/lo [C][R] bf16
__global__ __launch_bounds__(256) void k_cvt_t_hl(const float* __restrict__ src,
                                                  u16* __restrict__ hi,
                                                  u16* __restrict__ lo,
                                                  int R, int C) {
  const int z = blockIdx.z;
  src += (size_t)z * R * C;
  hi += (size_t)z * R * C;
  lo += (size_t)z * R * C;
  const int r0 = blockIdx.y * 64, c0 = blockIdx.x * 64;
  __shared__ u16 th[64][65], tl[64][65];
  const int t = threadIdx.x;
  const int cc = t & 63, rb = t >> 6;
#pragma unroll
  for (int i = 0; i < 16; ++i) {
    const int r = i * 4 + rb;
    const float f = src[(size_t)(r0 + r) * C + c0 + cc];
    const u16 h = f2b(f);
    th[r][cc] = h;
    tl[r][cc] = f2b(f - b2f(h));
  }
  __syncthreads();
#pragma unroll
  for (int i = 0; i < 16; ++i) {
    const int r = i * 4 + rb;
    hi[(size_t)(c0 + r) * R + r0 + cc] = th[cc][r];
    lo[(size_t)(c0 + r) * R + r0 + cc] = tl[cc][r];
  }
}

// ------- split-bf16 dense MFMA GEMM, 128x128 tile, BK=64, 4 waves ---------
// LDS tiles XOR-swizzled (chunk ^= row&7) via pre-swizzled per-lane global
// source (global_load_lds dest is linear; source address is per-lane).
template <int TERMS, int EP>
__global__ __launch_bounds__(256) void k_gemm_sp(
    const u16* __restrict__ Ah, const u16* __restrict__ Al,
    const u16* __restrict__ Bh, const u16* __restrict__ Bl,
    const float* __restrict__ bias, const float* __restrict__ addv,
    const float* __restrict__ addm, float* __restrict__ outF,
    u16* __restrict__ outH, u16* __restrict__ outL,
    u16* __restrict__ outVH, u16* __restrict__ outVL, int K, int N,
    size_t aStride, size_t bStride, size_t cStride) {
  const int z = blockIdx.z;
  Ah += (size_t)z * aStride;
  if (TERMS == 3) Al += (size_t)z * aStride;
  Bh += (size_t)z * bStride;
  Bl += (size_t)z * bStride;
  const int m0 = blockIdx.y * 128, n0 = blockIdx.x * 128;
  __shared__ u16 Ash[128][64];
  __shared__ u16 Asl[(TERMS == 3) ? 128 : 1][64];
  __shared__ u16 Bsh[128][64];
  __shared__ u16 Bsl[128][64];
  const int t = threadIdx.x;
  const int w = t >> 6, l = t & 63;
  const int srow = w * 8 + (l >> 3);
  // swizzled source chunk: LDS row&7 == l>>3, so src chunk = (l&7)^(l>>3)
  const int sscol = ((l & 7) ^ (l >> 3)) * 8;
  size_t aoff[4], boff[4];
#pragma unroll
  for (int i = 0; i < 4; ++i) {
    aoff[i] = (size_t)(m0 + i * 32 + srow) * K + sscol;
    boff[i] = (size_t)(n0 + i * 32 + srow) * K + sscol;
  }
  const int wr = w >> 1, wc = w & 1;
  const int lr = l & 15, lg = l >> 4;
  f32x4_t acc[4][4] = {};
  for (int k0 = 0; k0 < K; k0 += 64) {
#pragma unroll
    for (int i = 0; i < 4; ++i) {
      gl_lds16(Ah + aoff[i] + k0, &Ash[i * 32 + w * 8][0]);
      if (TERMS == 3) gl_lds16(Al + aoff[i] + k0, &Asl[i * 32 + w * 8][0]);
      gl_lds16(Bh + boff[i] + k0, &Bsh[i * 32 + w * 8][0]);
      gl_lds16(Bl + boff[i] + k0, &Bsl[i * 32 + w * 8][0]);
    }
    __syncthreads();  // drains vmcnt: tiles staged
#pragma unroll
    for (int kk = 0; kk < 2; ++kk) {
      const int cs = (kk * 32 + lg * 8) ^ ((lr & 7) << 3);  // swizzled read
      bf16x8_t ah[4], al[4], bh[4], bl[4];
#pragma unroll
      for (int m = 0; m < 4; ++m) {
        ah[m] = *(const bf16x8_t*)&Ash[wr * 64 + m * 16 + lr][cs];
        if (TERMS == 3)
          al[m] = *(const bf16x8_t*)&Asl[wr * 64 + m * 16 + lr][cs];
      }
#pragma unroll
      for (int n = 0; n < 4; ++n) {
        bh[n] = *(const bf16x8_t*)&Bsh[wc * 64 + n * 16 + lr][cs];
        bl[n] = *(const bf16x8_t*)&Bsl[wc * 64 + n * 16 + lr][cs];
      }
#pragma unroll
      for (int m = 0; m < 4; ++m)
#pragma unroll
        for (int n = 0; n < 4; ++n) {
          acc[m][n] = __builtin_amdgcn_mfma_f32_16x16x32_bf16(ah[m], bh[n],
                                                              acc[m][n], 0, 0, 0);
          acc[m][n] = __builtin_amdgcn_mfma_f32_16x16x32_bf16(ah[m], bl[n],
                                                              acc[m][n], 0, 0, 0);
          if (TERMS == 3)
            acc[m][n] = __builtin_amdgcn_mfma_f32_16x16x32_bf16(
                al[m], bh[n], acc[m][n], 0, 0, 0);
        }
    }
    __syncthreads();
  }
  const size_t cb = (size_t)z * cStride;
#pragma unroll
  for (int m = 0; m < 4; ++m) {
#pragma unroll
    for (int n = 0; n < 4; ++n) {
      const int c = n0 + wc * 64 + n * 16 + lr;
#pragma unroll
      for (int j = 0; j < 4; ++j) {
        const int r = m0 + wr * 64 + m * 16 + lg * 4 + j;
        float v = acc[m][n][j];
        if (EP == 1) v += bias[c] + addv[c] + addm[(size_t)r * N + c];
        if (EP == 2 || EP == 4) v += bias[c];
        const size_t idx = cb + (size_t)r * N + c;
        if (EP == 1 || EP == 2) outF[idx] = v;
        if (EP == 0 || EP == 1) {
          const u16 h = f2b(v);
          outH[idx] = h;
          outL[idx] = f2b(v - b2f(h));
        }
        if (EP == 4) {
          if (c < DMODEL) v *= 0.125f;  // fold attn scale into Q (exact)
          const u16 h = f2b(v);
          const u16 lo = f2b(v - b2f(h));
          if (c < 2 * DMODEL) {
            outH[idx] = h;
            outL[idx] = lo;
          } else {
            // V: [b][h][tile][d][64] transposed, k-permuted, XOR-swizzled
            const int d = (c - 2 * DMODEL) & 63;
            const int hd = (c - 2 * DMODEL) >> 6;
            const int bb = r >> 10;
            const int tile = (r & 1023) >> 6;
            const int tv = r & 63;
            const int cc2 = 4 * (tv & 15) + (tv >> 4);   // k-permutation
            const int stc = cc2 ^ ((d & 7) << 3);        // XOR swizzle
            const size_t vo =
                (((size_t)(bb * 8 + hd) * 16 + tile) * 64 + d) * 64 + stc;
            outVH[vo] = h;
            outVL[vo] = lo;
          }
        }
      }
    }
  }
}

// -------- Flash attention: 128 q-rows/block, reg-prefetched K/V ------------
__global__ __launch_bounds__(256) void k_attn(const u16* __restrict__ qh_g,
                                              const u16* __restrict__ ql_g,
                                              const u16* __restrict__ vph,
                                              const u16* __restrict__ vpl,
                                              u16* __restrict__ oh_g,
                                              u16* __restrict__ ol_g) {
  const int q0 = blockIdx.x * 128, h = blockIdx.y, b = blockIdx.z;
  const int t = threadIdx.x;
  const int w = t >> 6, l = t & 63;
  const int lr = l & 15, lg = l >> 4;
  __shared__ u16 Ksh[64][64], Ksl[64][64];
  __shared__ u16 Vth[64][64], Vtl[64][64];
  __shared__ u16 Psh[128][64], Psl[128][64];
  u16* VthF = &Vth[0][0];
  u16* VtlF = &Vtl[0][0];
  // Q fragments per subtile (row = q0 + s*64 + w*16 + lr)
  bf16x8_t qh[2][2], ql[2][2];
#pragma unroll
  for (int s = 0; s < 2; ++s) {
    const size_t qoff =
        (size_t)(b * NSEQ + q0 + s * 64 + w * 16 + lr) * (3 * DMODEL) +
        h * HDIM;
#pragma unroll
    for (int kc = 0; kc < 2; ++kc) {
      qh[s][kc] = *(const bf16x8_t*)(qh_g + qoff + kc * 32 + lg * 8);
      ql[s][kc] = *(const bf16x8_t*)(ql_g + qoff + kc * 32 + lg * 8);
    }
  }
  float mrow[2][4], lrow[2][4];
#pragma unroll
  for (int s = 0; s < 2; ++s)
#pragma unroll
    for (int j = 0; j < 4; ++j) { mrow[s][j] = -1e30f; lrow[s][j] = 0.f; }
  f32x4_t acc_o[2][4] = {};
  const int sr = t >> 2;          // K staging row (kv index)
  const int sc = (t & 3) * 16;    // K staging col chunk
  const int cs0 = sc ^ ((sr & 7) << 3);
  const int cs1 = (sc + 8) ^ ((sr & 7) << 3);
  const size_t vbh = ((size_t)(b * 8 + h) * 16) * 4096;
  const int vsub = w * 512 + l * 8;  // per-lane offset (u16 units)
  // prefetch registers for tile 0
  uint4 pkh0, pkh1, pkl0, pkl1, pvh0, pvh1, pvl0, pvl1;
  {
    const size_t kro =
        (size_t)(b * NSEQ + sr) * (3 * DMODEL) + DMODEL + h * HDIM + sc;
    pkh0 = *(const uint4*)(qh_g + kro);
    pkh1 = *(const uint4*)(qh_g + kro + 8);
    pkl0 = *(const uint4*)(ql_g + kro);
    pkl1 = *(const uint4*)(ql_g + kro + 8);
    pvh0 = *(const uint4*)(vph + vbh + vsub);
    pvh1 = *(const uint4*)(vph + vbh + 2048 + vsub);
    pvl0 = *(const uint4*)(vpl + vbh + vsub);
    pvl1 = *(const uint4*)(vpl + vbh + 2048 + vsub);
  }
  for (int k0 = 0; k0 < NSEQ; k0 += 64) {
    __syncthreads();  // A: prev tile reads done; prefetch regs ready
    *(uint4*)&Ksh[sr][cs0] = pkh0;
    *(uint4*)&Ksh[sr][cs1] = pkh1;
    *(uint4*)&Ksl[sr][cs0] = pkl0;
    *(uint4*)&Ksl[sr][cs1] = pkl1;
    *(uint4*)(VthF + vsub) = pvh0;
    *(uint4*)(VthF + 2048 + vsub) = pvh1;
    *(uint4*)(VtlF + vsub) = pvl0;
    *(uint4*)(VtlF + 2048 + vsub) = pvl1;
    __syncthreads();  // B: K/V staged
    if (k0 + 64 < NSEQ) {  // issue next tile's loads (hide under compute)
      const size_t kro = (size_t)(b * NSEQ + k0 + 64 + sr) * (3 * DMODEL) +
                         DMODEL + h * HDIM + sc;
      pkh0 = *(const uint4*)(qh_g + kro);
      pkh1 = *(const uint4*)(qh_g + kro + 8);
      pkl0 = *(const uint4*)(ql_g + kro);
      pkl1 = *(const uint4*)(ql_g + kro + 8);
      const size_t vt = vbh + (size_t)((k0 >> 6) + 1) * 4096;
      pvh0 = *(const uint4*)(vph + vt + vsub);
      pvh1 = *(const uint4*)(vph + vt + 2048 + vsub);
      pvl0 = *(const uint4*)(vpl + vt + vsub);
      pvl1 = *(const uint4*)(vpl + vt + 2048 + vsub);
    }
    // --- S = Q K^T (split 3-term), K from LDS, both subtiles
    f32x4_t sacc[2][4] = {};
    __builtin_amdgcn_s_setprio(1);
#pragma unroll
    for (int kc = 0; kc < 2; ++kc) {
      const int cs = (kc * 32 + lg * 8) ^ ((lr & 7) << 3);
#pragma unroll
      for (int n = 0; n < 4; ++n) {
        const bf16x8_t kh = *(const bf16x8_t*)&Ksh[n * 16 + lr][cs];
        const bf16x8_t kl = *(const bf16x8_t*)&Ksl[n * 16 + lr][cs];
#pragma unroll
        for (int s = 0; s < 2; ++s) {
          sacc[s][n] = __builtin_amdgcn_mfma_f32_16x16x32_bf16(
              qh[s][kc], kh, sacc[s][n], 0, 0, 0);
          sacc[s][n] = __builtin_amdgcn_mfma_f32_16x16x32_bf16(
              qh[s][kc], kl, sacc[s][n], 0, 0, 0);
          sacc[s][n] = __builtin_amdgcn_mfma_f32_16x16x32_bf16(
              ql[s][kc], kh, sacc[s][n], 0, 0, 0);
        }
      }
    }
    __builtin_amdgcn_s_setprio(0);
    // --- online softmax per subtile; P k-permuted packed stores
#pragma unroll
    for (int s = 0; s < 2; ++s) {
      float alpha[4];
#pragma unroll
      for (int j = 0; j < 4; ++j) {
        float mx = fmaxf(fmaxf(sacc[s][0][j], sacc[s][1][j]),
                         fmaxf(sacc[s][2][j], sacc[s][3][j]));
        mx = fmaxf(mx, __shfl_xor(mx, 1));
        mx = fmaxf(mx, __shfl_xor(mx, 2));
        mx = fmaxf(mx, __shfl_xor(mx, 4));
        mx = fmaxf(mx, __shfl_xor(mx, 8));
        const float mnew = fmaxf(mrow[s][j], mx);
        alpha[j] = __expf(mrow[s][j] - mnew);
        mrow[s][j] = mnew;
        float psum = 0.f;
        const int prow = lg * 4 + j;
        ushort4 ph4, pl4;
        u16* php = (u16*)&ph4;
        u16* plp = (u16*)&pl4;
#pragma unroll
        for (int n = 0; n < 4; ++n) {
          const float p = __expf(sacc[s][n][j] - mnew);
          psum += p;
          const u16 hi = f2b(p);
          php[n] = hi;
          plp[n] = f2b(p - b2f(hi));
        }
        const int pc = (4 * lr) ^ ((prow & 7) << 3);
        *(ushort4*)&Psh[s * 64 + w * 16 + prow][pc] = ph4;
        *(ushort4*)&Psl[s * 64 + w * 16 + prow][pc] = pl4;
        psum += __shfl_xor(psum, 1);
        psum += __shfl_xor(psum, 2);
        psum += __shfl_xor(psum, 4);
        psum += __shfl_xor(psum, 8);
        lrow[s][j] = lrow[s][j] * alpha[j] + psum;
      }
#pragma unroll
      for (int n = 0; n < 4; ++n)
#pragma unroll
        for (int j = 0; j < 4; ++j) acc_o[s][n][j] *= alpha[j];
    }
    // --- O += P V (split 3-term); P rows wave-private; k-order matches V
    __builtin_amdgcn_s_setprio(1);
#pragma unroll
    for (int kc = 0; kc < 2; ++kc) {
      const int cs = (kc * 32 + lg * 8) ^ ((lr & 7) << 3);
      bf16x8_t ph[2], pl[2];
#pragma unroll
      for (int s = 0; s < 2; ++s) {
        ph[s] = *(const bf16x8_t*)&Psh[s * 64 + w * 16 + lr][cs];
        pl[s] = *(const bf16x8_t*)&Psl[s * 64 + w * 16 + lr][cs];
      }
#pragma unroll
      for (int n = 0; n < 4; ++n) {
        const bf16x8_t vh = *(const bf16x8_t*)&Vth[n * 16 + lr][cs];
        const bf16x8_t vl = *(const bf16x8_t*)&Vtl[n * 16 + lr][cs];
#pragma unroll
        for (int s = 0; s < 2; ++s) {
          acc_o[s][n] = __builtin_amdgcn_mfma_f32_16x16x32_bf16(
              ph[s], vh, acc_o[s][n], 0, 0, 0);
          acc_o[s][n] = __builtin_amdgcn_mfma_f32_16x16x32_bf16(
              ph[s], vl, acc_o[s][n], 0, 0, 0);
          acc_o[s][n] = __builtin_amdgcn_mfma_f32_16x16x32_bf16(
              pl[s], vh, acc_o[s][n], 0, 0, 0);
        }
      }
    }
    __builtin_amdgcn_s_setprio(0);
  }
  // --- epilogue: write hi/lo bf16 directly
#pragma unroll
  for (int s = 0; s < 2; ++s) {
#pragma unroll
    for (int j = 0; j < 4; ++j) {
      const float invl = 1.0f / lrow[s][j];
      const size_t ro =
          (size_t)(b * NSEQ + q0 + s * 64 + w * 16 + lg * 4 + j) * DMODEL +
          h * HDIM;
#pragma unroll
      for (int n = 0; n < 4; ++n) {
        const float v = acc_o[s][n][j] * invl;
        const u16 hh = f2b(v);
        oh_g[ro + n * 16 + lr] = hh;
        ol_g[ro + n * 16 + lr] = f2b(v - b2f(hh));
      }
    }
  }
}

// ------- LayerNorm( a + b ) -> x2 (f32) + x2b (bf16) + fused MoE gate ------
__global__ __launch_bounds__(256) void k_ln_add(
    const float* __restrict__ a, const float* __restrict__ bsrc,
    const float* __restrict__ g, const float* __restrict__ be,
    const float* __restrict__ gw, float* __restrict__ outp,
    u16* __restrict__ outb, int* __restrict__ eidx,
    float* __restrict__ ewgt) {
  const int tok = blockIdx.x;
  const int t = threadIdx.x;
  float2 v;
  {
    const float2 va = *(const float2*)(a + (size_t)tok * DMODEL + t * 2);
    const float2 vb = *(const float2*)(bsrc + (size_t)tok * DMODEL + t * 2);
    v.x = va.x + vb.x; v.y = va.y + vb.y;
  }
  float s1 = v.x + v.y, s2 = v.x * v.x + v.y * v.y;
#pragma unroll
  for (int o = 32; o; o >>= 1) { s1 += __shfl_down(s1, o); s2 += __shfl_down(s2, o); }
  __shared__ float sm1[4], sm2[4];
  __shared__ float smg[4][NEXP];
  if ((t & 63) == 0) { sm1[t >> 6] = s1; sm2[t >> 6] = s2; }
  __syncthreads();
  s1 = sm1[0] + sm1[1] + sm1[2] + sm1[3];
  s2 = sm2[0] + sm2[1] + sm2[2] + sm2[3];
  const float mean = s1 * (1.f / DMODEL);
  const float var = s2 * (1.f / DMODEL) - mean * mean;
  const float rstd = rsqrtf(var + 1e-5f);
  float2 o;
  o.x = (v.x - mean) * rstd * g[t * 2] + be[t * 2];
  o.y = (v.y - mean) * rstd * g[t * 2 + 1] + be[t * 2 + 1];
  *(float2*)(outp + (size_t)tok * DMODEL + t * 2) = o;
  ushort2 ob;
  ob.x = f2b(o.x); ob.y = f2b(o.y);
  *(ushort2*)(outb + (size_t)tok * DMODEL + t * 2) = ob;
  // --- fused gate: per-thread partial dots, butterfly, thread-0 top-2
  float p[NEXP];
#pragma unroll
  for (int e = 0; e < NEXP; ++e) {
    const float2 wv = *(const float2*)(gw + e * DMODEL + t * 2);
    p[e] = o.x * wv.x + o.y * wv.y;
  }
#pragma unroll
  for (int e = 0; e < NEXP; ++e) {
    p[e] += __shfl_xor(p[e], 1);
    p[e] += __shfl_xor(p[e], 2);
    p[e] += __shfl_xor(p[e], 4);
    p[e] += __shfl_xor(p[e], 8);
    p[e] += __shfl_xor(p[e], 16);
    p[e] += __shfl_xor(p[e], 32);
  }
  if ((t & 63) == 0) {
#pragma unroll
    for (int e = 0; e < NEXP; ++e) smg[t >> 6][e] = p[e];
  }
  __syncthreads();
  if (t == 0) {
    float lg2[NEXP];
#pragma unroll
    for (int e = 0; e < NEXP; ++e)
      lg2[e] = smg[0][e] + smg[1][e] + smg[2][e] + smg[3][e];
    int i0 = 0; float b0 = lg2[0];
#pragma unroll
    for (int e = 1; e < NEXP; ++e) if (lg2[e] > b0) { b0 = lg2[e]; i0 = e; }
    int i1 = -1; float v1 = -1e30f;
#pragma unroll
    for (int e = 0; e < NEXP; ++e)
      if (e != i0 && lg2[e] > v1) { v1 = lg2[e]; i1 = e; }
    const float tt = __expf(v1 - b0);
    const float w0 = 1.f / (1.f + tt), w1 = tt / (1.f + tt);
    eidx[tok * 2] = i0; eidx[tok * 2 + 1] = i1;
    ewgt[tok * 2] = w0; ewgt[tok * 2 + 1] = w1;
  }
}

__global__ void k_zero(int* __restrict__ p, int n) {
  const int i = blockIdx.x * blockDim.x + threadIdx.x;
  if (i < n) p[i] = 0;
}

// ------- count experts: per-block LDS aggregation -> 8 global atomics ------
__global__ __launch_bounds__(256) void k_count(const int* __restrict__ eidx,
                                               int* __restrict__ ecnt) {
  __shared__ int cnt[NEXP];
  const int t = threadIdx.x;
  if (t < NEXP) cnt[t] = 0;
  __syncthreads();
  atomicAdd(&cnt[eidx[blockIdx.x * 256 + t]], 1);
  __syncthreads();
  if (t < NEXP) atomicAdd(&ecnt[t], cnt[t]);
}

// ------- offsets + dense block map: one entry per real 128-row tile --------
__global__ void k_offsets(const int* __restrict__ ecnt,
                          int* __restrict__ eoff, int* __restrict__ blkmap) {
  if (threadIdx.x == 0) {
    int s = 0;
    for (int e = 0; e < NEXP; ++e) { eoff[e] = s; s += ecnt[e]; }
    int nb = 0;
    for (int e = 0; e < NEXP; ++e)
      for (int m0 = 0; m0 < ecnt[e]; m0 += 128)
        blkmap[1 + nb++] = e | (m0 << 4);
    blkmap[0] = nb;
  }
}

// ------- scatter: LDS local pos + one block-level global atomic per expert -
__global__ __launch_bounds__(256) void k_scatter(
    const int* __restrict__ eidx, const int* __restrict__ eoff,
    int* __restrict__ efill, int* __restrict__ rtok, int* __restrict__ t2s) {
  __shared__ int lcnt[NEXP];
  __shared__ int lbase[NEXP];
  const int t = threadIdx.x;
  if (t < NEXP) lcnt[t] = 0;
  __syncthreads();
  const int tok = blockIdx.x * 128 + (t >> 1);
  const int k = t & 1;
  const int e = eidx[tok * 2 + k];
  const int lpos = atomicAdd(&lcnt[e], 1);
  __syncthreads();
  if (t < NEXP) lbase[t] = atomicAdd(&efill[t], lcnt[t]);
  __syncthreads();
  const int slot = eoff[e] + lbase[e] + lpos;
  rtok[slot] = tok;
  t2s[tok * 2 + k] = slot;
}

// ------------- transpose-convert f32 [R][C] -> bf16 [C][R], per expert -----
__global__ __launch_bounds__(256) void k_cvt_t(const float* __restrict__ src,
                                               u16* __restrict__ dst,
                                               int R, int C) {
  const int e = blockIdx.z;
  src += (size_t)e * R * C;
  dst += (size_t)e * R * C;
  const int r0 = blockIdx.y * 64, c0 = blockIdx.x * 64;
  __shared__ u16 tile[64][65];
  const int t = threadIdx.x;
  const int cc = t & 63, rb = t >> 6;
#pragma unroll
  for (int i = 0; i < 16; ++i) {
    const int r = i * 4 + rb;
    tile[r][cc] = f2b(src[(size_t)(r0 + r) * C + c0 + cc]);
  }
  __syncthreads();
#pragma unroll
  for (int i = 0; i < 16; ++i) {
    const int r = i * 4 + rb;
    dst[(size_t)(c0 + r) * R + r0 + cc] = tile[cc][r];
  }
}

// ------------- MoE MFMA GEMM, 128x256 tile, BK=64, 4 waves (2x2) -----------
// N-doubled tile: 64 MFMA per 48KB stage (vs 32 per 32KB) amortizes the
// stage+drain+barrier cost. Dense block map; XOR-swizzled LDS.
template <int MODE>
__global__ __launch_bounds__(256) void k_moe_mfma(
    const u16* __restrict__ Ab, const u16* __restrict__ Bb,
    const float* __restrict__ bias, const int* __restrict__ rtok,
    const int* __restrict__ ecnt, const int* __restrict__ eoff,
    const int* __restrict__ blkmap, u16* __restrict__ outp) {
  constexpr int K = (MODE == 0) ? DMODEL : DF;
  constexpr int N = (MODE == 0) ? DF : DMODEL;
  const int nb = blkmap[0];
  if ((int)blockIdx.y >= nb) return;
  const int ent = blkmap[1 + blockIdx.y];
  const int e = ent & 15;
  const int m0 = ent >> 4;
  const int cnt = ecnt[e];
  const int off = eoff[e];
  const int n0 = blockIdx.x * 256;
  const u16* Bw = Bb + (size_t)e * (size_t)K * N;  // [N][K] bf16
  __shared__ u16 As[128][64];
  __shared__ u16 Bs[256][64];
  const int t = threadIdx.x;
  const int w = t >> 6, l = t & 63;
  const int srow = w * 8 + (l >> 3);
  const int sscol = ((l & 7) ^ (l >> 3)) * 8;  // swizzled source chunk
  const u16* arow[4];
#pragma unroll
  for (int i = 0; i < 4; ++i) {
    const int r = m0 + i * 32 + srow;
    const int rr = (r < cnt) ? r : (cnt - 1);
    if (MODE == 0)
      arow[i] = Ab + (size_t)rtok[off + rr] * K + sscol;
    else
      arow[i] = Ab + ((size_t)off + rr) * K + sscol;
  }
  const u16* brow[8];
#pragma unroll
  for (int i = 0; i < 8; ++i)
    brow[i] = Bw + (size_t)(n0 + i * 32 + srow) * K + sscol;

  const int wr = w >> 1, wc = w & 1;
  const int lr = l & 15, lg = l >> 4;
  f32x4_t acc[4][8] = {};
  for (int k0 = 0; k0 < K; k0 += 64) {
#pragma unroll
    for (int i = 0; i < 4; ++i)
      gl_lds16(arow[i] + k0, &As[i * 32 + w * 8][0]);
#pragma unroll
    for (int i = 0; i < 8; ++i)
      gl_lds16(brow[i] + k0, &Bs[i * 32 + w * 8][0]);
    __syncthreads();
#pragma unroll
    for (int kk = 0; kk < 2; ++kk) {
      const int cs = (kk * 32 + lg * 8) ^ ((lr & 7) << 3);  // swizzled read
      bf16x8_t af[4], bfr[8];
#pragma unroll
      for (int m = 0; m < 4; ++m)
        af[m] = *(const bf16x8_t*)&As[wr * 64 + m * 16 + lr][cs];
#pragma unroll
      for (int n = 0; n < 8; ++n)
        bfr[n] = *(const bf16x8_t*)&Bs[wc * 128 + n * 16 + lr][cs];
#pragma unroll
      for (int m = 0; m < 4; ++m)
#pragma unroll
        for (int n = 0; n < 8; ++n)
          acc[m][n] = __builtin_amdgcn_mfma_f32_16x16x32_bf16(
              af[m], bfr[n], acc[m][n], 0, 0, 0);
    }
    __syncthreads();
  }
#pragma unroll
  for (int m = 0; m < 4; ++m) {
    const int rl0 = wr * 64 + m * 16 + lg * 4;
#pragma unroll
    for (int n = 0; n < 8; ++n) {
      const int gc = n0 + wc * 128 + n * 16 + lr;
      const float bv = bias[e * N + gc];
#pragma unroll
      for (int j = 0; j < 4; ++j) {
        const int r = m0 + rl0 + j;
        if (r < cnt) {
          float v = acc[m][n][j] + bv;
          if (MODE == 0) v = v * 0.5f * (1.f + erff(v * 0.70710678118f));
          outp[((size_t)off + r) * N + gc] = f2b(v);
        }
      }
    }
  }
}

// -------- combine: out = LN( x2 + w0*y[s0] + w1*y[s1] ), y in bf16 ---------
__global__ __launch_bounds__(256) void k_ln2(
    const float* __restrict__ x2, const u16* __restrict__ ybuf,
    const int* __restrict__ t2s, const float* __restrict__ ewgt,
    const float* __restrict__ g, const float* __restrict__ be,
    float* __restrict__ outp) {
  const int tok = blockIdx.x;
  const int t = threadIdx.x;
  const int s0 = t2s[tok * 2], s1i = t2s[tok * 2 + 1];
  const float w0 = ewgt[tok * 2], w1 = ewgt[tok * 2 + 1];
  float2 v;
  {
    const float2 a = *(const float2*)(x2 + (size_t)tok * DMODEL + t * 2);
    const ushort2 y0 = *(const ushort2*)(ybuf + (size_t)s0 * DMODEL + t * 2);
    const ushort2 y1 = *(const ushort2*)(ybuf + (size_t)s1i * DMODEL + t * 2);
    v.x = a.x + w0 * b2f(y0.x) + w1 * b2f(y1.x);
    v.y = a.y + w0 * b2f(y0.y) + w1 * b2f(y1.y);
  }
  float sum1 = v.x + v.y, sum2 = v.x * v.x + v.y * v.y;
#pragma unroll
  for (int o = 32; o; o >>= 1) { sum1 += __shfl_down(sum1, o); sum2 += __shfl_down(sum2, o); }
  __shared__ float sm1[4], sm2[4];
  if ((t & 63) == 0) { sm1[t >> 6] = sum1; sm2[t >> 6] = sum2; }
  __syncthreads();
  sum1 = sm1[0] + sm1[1] + sm1[2] + sm1[3];
  sum2 = sm2[0] + sm2[1] + sm2[2] + sm2[3];
  const float mean = sum1 * (1.f / DMODEL);
  const float var = sum2 * (1.f / DMODEL) - mean * mean;
  const float rstd = rsqrtf(var + 1e-5f);
  float2 o;
  o.x = (v.x - mean) * rstd * g[t * 2] + be[t * 2];
  o.y = (v.y - mean) * rstd * g[t * 2 + 1] + be[t * 2 + 1];
  *(float2*)(outp + (size_t)tok * DMODEL + t * 2) = o;
}

extern "C" void kernel_launch(void* const* d_in, const int* in_sizes, int n_in,
                              void* d_out, int out_size, void* d_ws,
                              size_t ws_size, hipStream_t stream) {
  const float* x      = (const float*)d_in[0];
  const float* adj    = (const float*)d_in[1];
  const float* gc_w   = (const float*)d_in[2];
  const float* gc_b   = (const float*)d_in[3];
  const float* root   = (const float*)d_in[4];
  const float* in_w   = (const float*)d_in[5];
  const float* in_b   = (const float*)d_in[6];
  const float* out_w  = (const float*)d_in[7];
  const float* out_b  = (const float*)d_in[8];
  const float* ln1_g  = (const float*)d_in[9];
  const float* ln1_b  = (const float*)d_in[10];
  const float* ln2_g  = (const float*)d_in[11];
  const float* ln2_b  = (const float*)d_in[12];
  const float* gate_w = (const float*)d_in[13];
  const float* W1     = (const float*)d_in[14];
  const float* b1     = (const float*)d_in[15];
  const float* W2     = (const float*)d_in[16];
  const float* b2     = (const float*)d_in[17];
  float* outp = (float*)d_out;

  // ws layout (peak 112.3 MB); same as rounds 8-16.
  constexpr size_t MB = 1ull << 20;
  char* W = (char*)d_ws;
  u16*   adj_bf = (u16*)(W + 0);
  u16*   xht    = (u16*)(W + 16 * MB);
  u16*   xlt    = (u16*)(W + 24 * MB);
  u16*   axh    = (u16*)(W + 32 * MB);
  u16*   axl    = (u16*)(W + 40 * MB);
  float* x1     = (float*)(W + 48 * MB);
  u16*   x1h    = (u16*)(W + 64 * MB);
  u16*   x1l    = (u16*)(W + 72 * MB);
  u16*   qkvh   = (u16*)(W + 0);        // 24 MiB [r][1536] (V third unused)
  u16*   qkvl   = (u16*)(W + 24 * MB);  // 24 MiB
  u16*   vph    = (u16*)(W + 80 * MB);  // 8 MiB transposed V hi
  u16*   vpl    = (u16*)(W + 88 * MB);  // 8 MiB transposed V lo
  u16*   oatth  = (u16*)(W + 96 * MB);
  u16*   oattl  = (u16*)(W + 104 * MB);
  float* oproj  = (float*)(W + 0);      // 16 MiB (qkvh head dead after attn)
  float* x2     = (float*)(W + 96 * MB); // over dead oatt after oproj GEMM
  u16*   Wxb    = (u16*)(W + 80 * MB);  // over dead vp after attn
  u16*   hid    = (u16*)(W + 16 * MB);  // 64 MiB
  u16*   ybuf   = (u16*)(W + 0);        // 16 MiB (oproj dead after LN1)
  char*  misc   = W + 112 * MB;
  char*  Od     = (char*)d_out;
  u16*   gwh = (u16*)(Od + 0);
  u16*   gwl = (u16*)(Od + 512 * 1024);
  u16*   iwh = (u16*)(Od + 1 * MB);
  u16*   iwl = (u16*)(Od + 1 * MB + 1536 * 1024);
  u16*   owh = (u16*)(Od + 4 * MB);
  u16*   owl = (u16*)(Od + 4 * MB + 512 * 1024);
  u16*   x2b = (u16*)d_out;
  int*   eidx  = (int*)misc;
  float* ewgt  = (float*)(misc + 65536);
  int*   ecnt  = (int*)(misc + 131072);
  int*   eoff  = (int*)(misc + 131072 + 128);
  int*   efill = (int*)(misc + 131072 + 256);
  int*   rtok  = (int*)(misc + 131072 + 512);
  int*   t2s   = (int*)(misc + 131072 + 512 + 65536);
  int*   blkmap = (int*)(misc + 131072 + 512 + 131072);

  // conversions: adj (exact bf16), x^T hi/lo, weight splits
  k_cvt_b<<<dim3(8192), 256, 0, stream>>>(adj, adj_bf, NB * NSEQ * NSEQ / 4);
  k_cvt_t_hl<<<dim3(8, 16, 8), 256, 0, stream>>>(x, xht, xlt, NSEQ, DMODEL);
  k_cvt_hl<<<dim3(256), 256, 0, stream>>>(gc_w, gwh, gwl, DMODEL * DMODEL / 4);
  k_cvt_hl<<<dim3(768), 256, 0, stream>>>(in_w, iwh, iwl, 3 * DMODEL * DMODEL / 4);
  k_cvt_hl<<<dim3(256), 256, 0, stream>>>(out_w, owh, owl, DMODEL * DMODEL / 4);
  // A: ax = adj @ x  (2-term split MFMA, per batch) -> axh/axl
  k_gemm_sp<2, 0><<<dim3(4, 8, 8), 256, 0, stream>>>(
      adj_bf, nullptr, xht, xlt, nullptr, nullptr, nullptr, nullptr, axh, axl,
      nullptr, nullptr, NSEQ, DMODEL, (size_t)NSEQ * NSEQ,
      (size_t)DMODEL * NSEQ, (size_t)NSEQ * DMODEL);
  // B: x1 = x + ax @ gc_w^T + gc_b + root  -> x1 f32 + x1h/x1l
  k_gemm_sp<3, 1><<<dim3(4, 64, 1), 256, 0, stream>>>(
      axh, axl, gwh, gwl, gc_b, root, x, x1, x1h, x1l, nullptr, nullptr,
      DMODEL, DMODEL, 0, 0, 0);
  // C: qkv GEMM -> qkvh/qkvl (Q pre-scaled) + transposed V (vph/vpl)
  k_gemm_sp<3, 4><<<dim3(12, 64, 1), 256, 0, stream>>>(
      x1h, x1l, iwh, iwl, in_b, nullptr, nullptr, nullptr, qkvh, qkvl, vph,
      vpl, DMODEL, 3 * DMODEL, 0, 0, 0);
  // D: attention (128 q-rows/block, reg-prefetched K/V, setprio)
  k_attn<<<dim3(8, 8, 8), 256, 0, stream>>>(qkvh, qkvl, vph, vpl, oatth,
                                            oattl);
  // E: oproj = oatt @ out_w^T + out_b
  k_gemm_sp<3, 2><<<dim3(4, 64, 1), 256, 0, stream>>>(
      oatth, oattl, owh, owl, out_b, nullptr, nullptr, oproj, nullptr, nullptr,
      nullptr, nullptr, DMODEL, DMODEL, 0, 0, 0);
  // LN1 + fused gate: x2 (f32), x2b (bf16), eidx/ewgt
  k_ln_add<<<dim3(T_TOK), 256, 0, stream>>>(x1, oproj, ln1_g, ln1_b, gate_w,
                                            x2, x2b, eidx, ewgt);
  // MoE routing: count -> offsets(+blkmap) -> scatter
  k_zero<<<dim3(1), 128, 0, stream>>>((int*)(misc + 131072), 128);
  k_count<<<dim3(2 * T_TOK / 256), 256, 0, stream>>>(eidx, ecnt);
  k_offsets<<<dim3(1), 64, 0, stream>>>(ecnt, eoff, blkmap);
  k_scatter<<<dim3(T_TOK / 128), 256, 0, stream>>>(eidx, eoff, efill, rtok,
                                                   t2s);
  // MoE expert FFN (MFMA bf16, 128x256 tiles, dense block map)
  k_cvt_t<<<dim3(DF / 64, DMODEL / 64, NEXP), 256, 0, stream>>>(W1, Wxb,
                                                                DMODEL, DF);
  k_moe_mfma<0><<<dim3(DF / 256, 135, 1), 256, 0, stream>>>(
      x2b, Wxb, b1, rtok, ecnt, eoff, blkmap, hid);
  k_cvt_t<<<dim3(DMODEL / 64, DF / 64, NEXP), 256, 0, stream>>>(W2, Wxb, DF,
                                                                DMODEL);
  k_moe_mfma<1><<<dim3(DMODEL / 256, 135, 1), 256, 0, stream>>>(
      hid, Wxb, b2, rtok, ecnt, eoff, blkmap, ybuf);
  // combine + LN2 -> out
  k_ln2<<<dim3(T_TOK), 256, 0, stream>>>(x2, ybuf, t2s, ewgt, ln2_g, ln2_b,
                                         outp);
}

// Round 18
// 497.803 us; speedup vs baseline: 1.2253x; 1.2253x over previous
//
#include <hip/hip_runtime.h>
#include <hip/hip_bf16.h>

#define NB 8
#define NSEQ 1024
#define DMODEL 512
#define DF 2048
#define NEXP 8
#define NHEAD 8
#define HDIM 64
#define T_TOK (NB * NSEQ)

typedef unsigned short u16;
typedef float f32x4_t __attribute__((ext_vector_type(4)));
typedef __bf16 bf16x8_t __attribute__((ext_vector_type(8)));

__device__ __forceinline__ u16 f2b(float f) {
  __hip_bfloat16 h = __float2bfloat16(f);
  return *reinterpret_cast<u16*>(&h);
}
__device__ __forceinline__ float b2f(u16 u) {
  return __uint_as_float((unsigned)u << 16);
}
// async global->LDS, 16B per lane; lds ptr must be wave-uniform
__device__ __forceinline__ void gl_lds16(const u16* g, u16* l) {
  __builtin_amdgcn_global_load_lds(
      (const __attribute__((address_space(1))) unsigned int*)g,
      (__attribute__((address_space(3))) unsigned int*)l, 16, 0, 0);
}

// ---------------- elementwise conversions ----------------------------------
__global__ __launch_bounds__(256) void k_cvt_hl(const float* __restrict__ src,
                                                u16* __restrict__ hi,
                                                u16* __restrict__ lo, int n4) {
  const int i = blockIdx.x * 256 + threadIdx.x;
  if (i >= n4) return;
  const float4 v = ((const float4*)src)[i];
  ushort4 h, l;
  h.x = f2b(v.x); l.x = f2b(v.x - b2f(h.x));
  h.y = f2b(v.y); l.y = f2b(v.y - b2f(h.y));
  h.z = f2b(v.z); l.z = f2b(v.z - b2f(h.z));
  h.w = f2b(v.w); l.w = f2b(v.w - b2f(h.w));
  ((ushort4*)hi)[i] = h;
  ((ushort4*)lo)[i] = l;
}

__global__ __launch_bounds__(256) void k_cvt_b(const float* __restrict__ src,
                                               u16* __restrict__ dst, int n4) {
  const int i = blockIdx.x * 256 + threadIdx.x;
  if (i >= n4) return;
  const float4 v = ((const float4*)src)[i];
  ushort4 h;
  h.x = f2b(v.x); h.y = f2b(v.y); h.z = f2b(v.z); h.w = f2b(v.w);
  ((ushort4*)dst)[i] = h;
}

// transpose + split per batch: src [R][C] f32 -> hi/lo [C][R] bf16
__global__ __launch_bounds__(256) void k_cvt_t_hl(const float* __restrict__ src,
                                                  u16* __restrict__ hi,
                                                  u16* __restrict__ lo,
                                                  int R, int C) {
  const int z = blockIdx.z;
  src += (size_t)z * R * C;
  hi += (size_t)z * R * C;
  lo += (size_t)z * R * C;
  const int r0 = blockIdx.y * 64, c0 = blockIdx.x * 64;
  __shared__ u16 th[64][65], tl[64][65];
  const int t = threadIdx.x;
  const int cc = t & 63, rb = t >> 6;
#pragma unroll
  for (int i = 0; i < 16; ++i) {
    const int r = i * 4 + rb;
    const float f = src[(size_t)(r0 + r) * C + c0 + cc];
    const u16 h = f2b(f);
    th[r][cc] = h;
    tl[r][cc] = f2b(f - b2f(h));
  }
  __syncthreads();
#pragma unroll
  for (int i = 0; i < 16; ++i) {
    const int r = i * 4 + rb;
    hi[(size_t)(c0 + r) * R + r0 + cc] = th[cc][r];
    lo[(size_t)(c0 + r) * R + r0 + cc] = tl[cc][r];
  }
}

// ------- split-bf16 dense MFMA GEMM, 128x128 tile, BK=64, 4 waves ---------
// LDS tiles XOR-swizzled (chunk ^= row&7) via pre-swizzled per-lane global
// source (global_load_lds dest is linear; source address is per-lane).
template <int TERMS, int EP>
__global__ __launch_bounds__(256) void k_gemm_sp(
    const u16* __restrict__ Ah, const u16* __restrict__ Al,
    const u16* __restrict__ Bh, const u16* __restrict__ Bl,
    const float* __restrict__ bias, const float* __restrict__ addv,
    const float* __restrict__ addm, float* __restrict__ outF,
    u16* __restrict__ outH, u16* __restrict__ outL,
    u16* __restrict__ outVH, u16* __restrict__ outVL, int K, int N,
    size_t aStride, size_t bStride, size_t cStride) {
  const int z = blockIdx.z;
  Ah += (size_t)z * aStride;
  if (TERMS == 3) Al += (size_t)z * aStride;
  Bh += (size_t)z * bStride;
  Bl += (size_t)z * bStride;
  const int m0 = blockIdx.y * 128, n0 = blockIdx.x * 128;
  __shared__ u16 Ash[128][64];
  __shared__ u16 Asl[(TERMS == 3) ? 128 : 1][64];
  __shared__ u16 Bsh[128][64];
  __shared__ u16 Bsl[128][64];
  const int t = threadIdx.x;
  const int w = t >> 6, l = t & 63;
  const int srow = w * 8 + (l >> 3);
  // swizzled source chunk: LDS row&7 == l>>3, so src chunk = (l&7)^(l>>3)
  const int sscol = ((l & 7) ^ (l >> 3)) * 8;
  size_t aoff[4], boff[4];
#pragma unroll
  for (int i = 0; i < 4; ++i) {
    aoff[i] = (size_t)(m0 + i * 32 + srow) * K + sscol;
    boff[i] = (size_t)(n0 + i * 32 + srow) * K + sscol;
  }
  const int wr = w >> 1, wc = w & 1;
  const int lr = l & 15, lg = l >> 4;
  f32x4_t acc[4][4] = {};
  for (int k0 = 0; k0 < K; k0 += 64) {
#pragma unroll
    for (int i = 0; i < 4; ++i) {
      gl_lds16(Ah + aoff[i] + k0, &Ash[i * 32 + w * 8][0]);
      if (TERMS == 3) gl_lds16(Al + aoff[i] + k0, &Asl[i * 32 + w * 8][0]);
      gl_lds16(Bh + boff[i] + k0, &Bsh[i * 32 + w * 8][0]);
      gl_lds16(Bl + boff[i] + k0, &Bsl[i * 32 + w * 8][0]);
    }
    __syncthreads();  // drains vmcnt: tiles staged
#pragma unroll
    for (int kk = 0; kk < 2; ++kk) {
      const int cs = (kk * 32 + lg * 8) ^ ((lr & 7) << 3);  // swizzled read
      bf16x8_t ah[4], al[4], bh[4], bl[4];
#pragma unroll
      for (int m = 0; m < 4; ++m) {
        ah[m] = *(const bf16x8_t*)&Ash[wr * 64 + m * 16 + lr][cs];
        if (TERMS == 3)
          al[m] = *(const bf16x8_t*)&Asl[wr * 64 + m * 16 + lr][cs];
      }
#pragma unroll
      for (int n = 0; n < 4; ++n) {
        bh[n] = *(const bf16x8_t*)&Bsh[wc * 64 + n * 16 + lr][cs];
        bl[n] = *(const bf16x8_t*)&Bsl[wc * 64 + n * 16 + lr][cs];
      }
#pragma unroll
      for (int m = 0; m < 4; ++m)
#pragma unroll
        for (int n = 0; n < 4; ++n) {
          acc[m][n] = __builtin_amdgcn_mfma_f32_16x16x32_bf16(ah[m], bh[n],
                                                              acc[m][n], 0, 0, 0);
          acc[m][n] = __builtin_amdgcn_mfma_f32_16x16x32_bf16(ah[m], bl[n],
                                                              acc[m][n], 0, 0, 0);
          if (TERMS == 3)
            acc[m][n] = __builtin_amdgcn_mfma_f32_16x16x32_bf16(
                al[m], bh[n], acc[m][n], 0, 0, 0);
        }
    }
    __syncthreads();
  }
  const size_t cb = (size_t)z * cStride;
#pragma unroll
  for (int m = 0; m < 4; ++m) {
#pragma unroll
    for (int n = 0; n < 4; ++n) {
      const int c = n0 + wc * 64 + n * 16 + lr;
#pragma unroll
      for (int j = 0; j < 4; ++j) {
        const int r = m0 + wr * 64 + m * 16 + lg * 4 + j;
        float v = acc[m][n][j];
        if (EP == 1) v += bias[c] + addv[c] + addm[(size_t)r * N + c];
        if (EP == 2 || EP == 4) v += bias[c];
        const size_t idx = cb + (size_t)r * N + c;
        if (EP == 1 || EP == 2) outF[idx] = v;
        if (EP == 0 || EP == 1) {
          const u16 h = f2b(v);
          outH[idx] = h;
          outL[idx] = f2b(v - b2f(h));
        }
        if (EP == 4) {
          if (c < DMODEL) v *= 0.125f;  // fold attn scale into Q (exact)
          const u16 h = f2b(v);
          const u16 lo = f2b(v - b2f(h));
          if (c < 2 * DMODEL) {
            outH[idx] = h;
            outL[idx] = lo;
          } else {
            // V: [b][h][tile][d][64] transposed, k-permuted, XOR-swizzled
            const int d = (c - 2 * DMODEL) & 63;
            const int hd = (c - 2 * DMODEL) >> 6;
            const int bb = r >> 10;
            const int tile = (r & 1023) >> 6;
            const int tv = r & 63;
            const int cc2 = 4 * (tv & 15) + (tv >> 4);   // k-permutation
            const int stc = cc2 ^ ((d & 7) << 3);        // XOR swizzle
            const size_t vo =
                (((size_t)(bb * 8 + hd) * 16 + tile) * 64 + d) * 64 + stc;
            outVH[vo] = h;
            outVL[vo] = lo;
          }
        }
      }
    }
  }
}

// -------- Flash attention: 128 q-rows/block, reg-prefetched K/V ------------
__global__ __launch_bounds__(256) void k_attn(const u16* __restrict__ qh_g,
                                              const u16* __restrict__ ql_g,
                                              const u16* __restrict__ vph,
                                              const u16* __restrict__ vpl,
                                              u16* __restrict__ oh_g,
                                              u16* __restrict__ ol_g) {
  const int q0 = blockIdx.x * 128, h = blockIdx.y, b = blockIdx.z;
  const int t = threadIdx.x;
  const int w = t >> 6, l = t & 63;
  const int lr = l & 15, lg = l >> 4;
  __shared__ u16 Ksh[64][64], Ksl[64][64];
  __shared__ u16 Vth[64][64], Vtl[64][64];
  __shared__ u16 Psh[128][64], Psl[128][64];
  u16* VthF = &Vth[0][0];
  u16* VtlF = &Vtl[0][0];
  // Q fragments per subtile (row = q0 + s*64 + w*16 + lr)
  bf16x8_t qh[2][2], ql[2][2];
#pragma unroll
  for (int s = 0; s < 2; ++s) {
    const size_t qoff =
        (size_t)(b * NSEQ + q0 + s * 64 + w * 16 + lr) * (3 * DMODEL) +
        h * HDIM;
#pragma unroll
    for (int kc = 0; kc < 2; ++kc) {
      qh[s][kc] = *(const bf16x8_t*)(qh_g + qoff + kc * 32 + lg * 8);
      ql[s][kc] = *(const bf16x8_t*)(ql_g + qoff + kc * 32 + lg * 8);
    }
  }
  float mrow[2][4], lrow[2][4];
#pragma unroll
  for (int s = 0; s < 2; ++s)
#pragma unroll
    for (int j = 0; j < 4; ++j) { mrow[s][j] = -1e30f; lrow[s][j] = 0.f; }
  f32x4_t acc_o[2][4] = {};
  const int sr = t >> 2;          // K staging row (kv index)
  const int sc = (t & 3) * 16;    // K staging col chunk
  const int cs0 = sc ^ ((sr & 7) << 3);
  const int cs1 = (sc + 8) ^ ((sr & 7) << 3);
  const size_t vbh = ((size_t)(b * 8 + h) * 16) * 4096;
  const int vsub = w * 512 + l * 8;  // per-lane offset (u16 units)
  // prefetch registers for tile 0
  uint4 pkh0, pkh1, pkl0, pkl1, pvh0, pvh1, pvl0, pvl1;
  {
    const size_t kro =
        (size_t)(b * NSEQ + sr) * (3 * DMODEL) + DMODEL + h * HDIM + sc;
    pkh0 = *(const uint4*)(qh_g + kro);
    pkh1 = *(const uint4*)(qh_g + kro + 8);
    pkl0 = *(const uint4*)(ql_g + kro);
    pkl1 = *(const uint4*)(ql_g + kro + 8);
    pvh0 = *(const uint4*)(vph + vbh + vsub);
    pvh1 = *(const uint4*)(vph + vbh + 2048 + vsub);
    pvl0 = *(const uint4*)(vpl + vbh + vsub);
    pvl1 = *(const uint4*)(vpl + vbh + 2048 + vsub);
  }
  for (int k0 = 0; k0 < NSEQ; k0 += 64) {
    __syncthreads();  // A: prev tile reads done; prefetch regs ready
    *(uint4*)&Ksh[sr][cs0] = pkh0;
    *(uint4*)&Ksh[sr][cs1] = pkh1;
    *(uint4*)&Ksl[sr][cs0] = pkl0;
    *(uint4*)&Ksl[sr][cs1] = pkl1;
    *(uint4*)(VthF + vsub) = pvh0;
    *(uint4*)(VthF + 2048 + vsub) = pvh1;
    *(uint4*)(VtlF + vsub) = pvl0;
    *(uint4*)(VtlF + 2048 + vsub) = pvl1;
    __syncthreads();  // B: K/V staged
    if (k0 + 64 < NSEQ) {  // issue next tile's loads (hide under compute)
      const size_t kro = (size_t)(b * NSEQ + k0 + 64 + sr) * (3 * DMODEL) +
                         DMODEL + h * HDIM + sc;
      pkh0 = *(const uint4*)(qh_g + kro);
      pkh1 = *(const uint4*)(qh_g + kro + 8);
      pkl0 = *(const uint4*)(ql_g + kro);
      pkl1 = *(const uint4*)(ql_g + kro + 8);
      const size_t vt = vbh + (size_t)((k0 >> 6) + 1) * 4096;
      pvh0 = *(const uint4*)(vph + vt + vsub);
      pvh1 = *(const uint4*)(vph + vt + 2048 + vsub);
      pvl0 = *(const uint4*)(vpl + vt + vsub);
      pvl1 = *(const uint4*)(vpl + vt + 2048 + vsub);
    }
    // --- S = Q K^T (split 3-term), K from LDS, both subtiles
    f32x4_t sacc[2][4] = {};
    __builtin_amdgcn_s_setprio(1);
#pragma unroll
    for (int kc = 0; kc < 2; ++kc) {
      const int cs = (kc * 32 + lg * 8) ^ ((lr & 7) << 3);
#pragma unroll
      for (int n = 0; n < 4; ++n) {
        const bf16x8_t kh = *(const bf16x8_t*)&Ksh[n * 16 + lr][cs];
        const bf16x8_t kl = *(const bf16x8_t*)&Ksl[n * 16 + lr][cs];
#pragma unroll
        for (int s = 0; s < 2; ++s) {
          sacc[s][n] = __builtin_amdgcn_mfma_f32_16x16x32_bf16(
              qh[s][kc], kh, sacc[s][n], 0, 0, 0);
          sacc[s][n] = __builtin_amdgcn_mfma_f32_16x16x32_bf16(
              qh[s][kc], kl, sacc[s][n], 0, 0, 0);
          sacc[s][n] = __builtin_amdgcn_mfma_f32_16x16x32_bf16(
              ql[s][kc], kh, sacc[s][n], 0, 0, 0);
        }
      }
    }
    __builtin_amdgcn_s_setprio(0);
    // --- online softmax per subtile; P k-permuted packed stores
#pragma unroll
    for (int s = 0; s < 2; ++s) {
      float alpha[4];
#pragma unroll
      for (int j = 0; j < 4; ++j) {
        float mx = fmaxf(fmaxf(sacc[s][0][j], sacc[s][1][j]),
                         fmaxf(sacc[s][2][j], sacc[s][3][j]));
        mx = fmaxf(mx, __shfl_xor(mx, 1));
        mx = fmaxf(mx, __shfl_xor(mx, 2));
        mx = fmaxf(mx, __shfl_xor(mx, 4));
        mx = fmaxf(mx, __shfl_xor(mx, 8));
        const float mnew = fmaxf(mrow[s][j], mx);
        alpha[j] = __expf(mrow[s][j] - mnew);
        mrow[s][j] = mnew;
        float psum = 0.f;
        const int prow = lg * 4 + j;
        ushort4 ph4, pl4;
        u16* php = (u16*)&ph4;
        u16* plp = (u16*)&pl4;
#pragma unroll
        for (int n = 0; n < 4; ++n) {
          const float p = __expf(sacc[s][n][j] - mnew);
          psum += p;
          const u16 hi = f2b(p);
          php[n] = hi;
          plp[n] = f2b(p - b2f(hi));
        }
        const int pc = (4 * lr) ^ ((prow & 7) << 3);
        *(ushort4*)&Psh[s * 64 + w * 16 + prow][pc] = ph4;
        *(ushort4*)&Psl[s * 64 + w * 16 + prow][pc] = pl4;
        psum += __shfl_xor(psum, 1);
        psum += __shfl_xor(psum, 2);
        psum += __shfl_xor(psum, 4);
        psum += __shfl_xor(psum, 8);
        lrow[s][j] = lrow[s][j] * alpha[j] + psum;
      }
#pragma unroll
      for (int n = 0; n < 4; ++n)
#pragma unroll
        for (int j = 0; j < 4; ++j) acc_o[s][n][j] *= alpha[j];
    }
    // --- O += P V (split 3-term); P rows wave-private; k-order matches V
    __builtin_amdgcn_s_setprio(1);
#pragma unroll
    for (int kc = 0; kc < 2; ++kc) {
      const int cs = (kc * 32 + lg * 8) ^ ((lr & 7) << 3);
      bf16x8_t ph[2], pl[2];
#pragma unroll
      for (int s = 0; s < 2; ++s) {
        ph[s] = *(const bf16x8_t*)&Psh[s * 64 + w * 16 + lr][cs];
        pl[s] = *(const bf16x8_t*)&Psl[s * 64 + w * 16 + lr][cs];
      }
#pragma unroll
      for (int n = 0; n < 4; ++n) {
        const bf16x8_t vh = *(const bf16x8_t*)&Vth[n * 16 + lr][cs];
        const bf16x8_t vl = *(const bf16x8_t*)&Vtl[n * 16 + lr][cs];
#pragma unroll
        for (int s = 0; s < 2; ++s) {
          acc_o[s][n] = __builtin_amdgcn_mfma_f32_16x16x32_bf16(
              ph[s], vh, acc_o[s][n], 0, 0, 0);
          acc_o[s][n] = __builtin_amdgcn_mfma_f32_16x16x32_bf16(
              ph[s], vl, acc_o[s][n], 0, 0, 0);
          acc_o[s][n] = __builtin_amdgcn_mfma_f32_16x16x32_bf16(
              pl[s], vh, acc_o[s][n], 0, 0, 0);
        }
      }
    }
    __builtin_amdgcn_s_setprio(0);
  }
  // --- epilogue: write hi/lo bf16 directly
#pragma unroll
  for (int s = 0; s < 2; ++s) {
#pragma unroll
    for (int j = 0; j < 4; ++j) {
      const float invl = 1.0f / lrow[s][j];
      const size_t ro =
          (size_t)(b * NSEQ + q0 + s * 64 + w * 16 + lg * 4 + j) * DMODEL +
          h * HDIM;
#pragma unroll
      for (int n = 0; n < 4; ++n) {
        const float v = acc_o[s][n][j] * invl;
        const u16 hh = f2b(v);
        oh_g[ro + n * 16 + lr] = hh;
        ol_g[ro + n * 16 + lr] = f2b(v - b2f(hh));
      }
    }
  }
}

// ------- LayerNorm( a + b ) -> x2 (f32) + x2b (bf16) + fused MoE gate ------
__global__ __launch_bounds__(256) void k_ln_add(
    const float* __restrict__ a, const float* __restrict__ bsrc,
    const float* __restrict__ g, const float* __restrict__ be,
    const float* __restrict__ gw, float* __restrict__ outp,
    u16* __restrict__ outb, int* __restrict__ eidx,
    float* __restrict__ ewgt) {
  const int tok = blockIdx.x;
  const int t = threadIdx.x;
  float2 v;
  {
    const float2 va = *(const float2*)(a + (size_t)tok * DMODEL + t * 2);
    const float2 vb = *(const float2*)(bsrc + (size_t)tok * DMODEL + t * 2);
    v.x = va.x + vb.x; v.y = va.y + vb.y;
  }
  float s1 = v.x + v.y, s2 = v.x * v.x + v.y * v.y;
#pragma unroll
  for (int o = 32; o; o >>= 1) { s1 += __shfl_down(s1, o); s2 += __shfl_down(s2, o); }
  __shared__ float sm1[4], sm2[4];
  __shared__ float smg[4][NEXP];
  if ((t & 63) == 0) { sm1[t >> 6] = s1; sm2[t >> 6] = s2; }
  __syncthreads();
  s1 = sm1[0] + sm1[1] + sm1[2] + sm1[3];
  s2 = sm2[0] + sm2[1] + sm2[2] + sm2[3];
  const float mean = s1 * (1.f / DMODEL);
  const float var = s2 * (1.f / DMODEL) - mean * mean;
  const float rstd = rsqrtf(var + 1e-5f);
  float2 o;
  o.x = (v.x - mean) * rstd * g[t * 2] + be[t * 2];
  o.y = (v.y - mean) * rstd * g[t * 2 + 1] + be[t * 2 + 1];
  *(float2*)(outp + (size_t)tok * DMODEL + t * 2) = o;
  ushort2 ob;
  ob.x = f2b(o.x); ob.y = f2b(o.y);
  *(ushort2*)(outb + (size_t)tok * DMODEL + t * 2) = ob;
  // --- fused gate: per-thread partial dots, butterfly, thread-0 top-2
  float p[NEXP];
#pragma unroll
  for (int e = 0; e < NEXP; ++e) {
    const float2 wv = *(const float2*)(gw + e * DMODEL + t * 2);
    p[e] = o.x * wv.x + o.y * wv.y;
  }
#pragma unroll
  for (int e = 0; e < NEXP; ++e) {
    p[e] += __shfl_xor(p[e], 1);
    p[e] += __shfl_xor(p[e], 2);
    p[e] += __shfl_xor(p[e], 4);
    p[e] += __shfl_xor(p[e], 8);
    p[e] += __shfl_xor(p[e], 16);
    p[e] += __shfl_xor(p[e], 32);
  }
  if ((t & 63) == 0) {
#pragma unroll
    for (int e = 0; e < NEXP; ++e) smg[t >> 6][e] = p[e];
  }
  __syncthreads();
  if (t == 0) {
    float lg2[NEXP];
#pragma unroll
    for (int e = 0; e < NEXP; ++e)
      lg2[e] = smg[0][e] + smg[1][e] + smg[2][e] + smg[3][e];
    int i0 = 0; float b0 = lg2[0];
#pragma unroll
    for (int e = 1; e < NEXP; ++e) if (lg2[e] > b0) { b0 = lg2[e]; i0 = e; }
    int i1 = -1; float v1 = -1e30f;
#pragma unroll
    for (int e = 0; e < NEXP; ++e)
      if (e != i0 && lg2[e] > v1) { v1 = lg2[e]; i1 = e; }
    const float tt = __expf(v1 - b0);
    const float w0 = 1.f / (1.f + tt), w1 = tt / (1.f + tt);
    eidx[tok * 2] = i0; eidx[tok * 2 + 1] = i1;
    ewgt[tok * 2] = w0; ewgt[tok * 2 + 1] = w1;
  }
}

__global__ void k_zero(int* __restrict__ p, int n) {
  const int i = blockIdx.x * blockDim.x + threadIdx.x;
  if (i < n) p[i] = 0;
}

// ------- count experts: per-block LDS aggregation -> 8 global atomics ------
__global__ __launch_bounds__(256) void k_count(const int* __restrict__ eidx,
                                               int* __restrict__ ecnt) {
  __shared__ int cnt[NEXP];
  const int t = threadIdx.x;
  if (t < NEXP) cnt[t] = 0;
  __syncthreads();
  atomicAdd(&cnt[eidx[blockIdx.x * 256 + t]], 1);
  __syncthreads();
  if (t < NEXP) atomicAdd(&ecnt[t], cnt[t]);
}

// ------- offsets + dense block map: one entry per real 128-row tile --------
__global__ void k_offsets(const int* __restrict__ ecnt,
                          int* __restrict__ eoff, int* __restrict__ blkmap) {
  if (threadIdx.x == 0) {
    int s = 0;
    for (int e = 0; e < NEXP; ++e) { eoff[e] = s; s += ecnt[e]; }
    int nb = 0;
    for (int e = 0; e < NEXP; ++e)
      for (int m0 = 0; m0 < ecnt[e]; m0 += 128)
        blkmap[1 + nb++] = e | (m0 << 4);
    blkmap[0] = nb;
  }
}

// ------- scatter: LDS local pos + one block-level global atomic per expert -
__global__ __launch_bounds__(256) void k_scatter(
    const int* __restrict__ eidx, const int* __restrict__ eoff,
    int* __restrict__ efill, int* __restrict__ rtok, int* __restrict__ t2s) {
  __shared__ int lcnt[NEXP];
  __shared__ int lbase[NEXP];
  const int t = threadIdx.x;
  if (t < NEXP) lcnt[t] = 0;
  __syncthreads();
  const int tok = blockIdx.x * 128 + (t >> 1);
  const int k = t & 1;
  const int e = eidx[tok * 2 + k];
  const int lpos = atomicAdd(&lcnt[e], 1);
  __syncthreads();
  if (t < NEXP) lbase[t] = atomicAdd(&efill[t], lcnt[t]);
  __syncthreads();
  const int slot = eoff[e] + lbase[e] + lpos;
  rtok[slot] = tok;
  t2s[tok * 2 + k] = slot;
}

// ------------- transpose-convert f32 [R][C] -> bf16 [C][R], per expert -----
__global__ __launch_bounds__(256) void k_cvt_t(const float* __restrict__ src,
                                               u16* __restrict__ dst,
                                               int R, int C) {
  const int e = blockIdx.z;
  src += (size_t)e * R * C;
  dst += (size_t)e * R * C;
  const int r0 = blockIdx.y * 64, c0 = blockIdx.x * 64;
  __shared__ u16 tile[64][65];
  const int t = threadIdx.x;
  const int cc = t & 63, rb = t >> 6;
#pragma unroll
  for (int i = 0; i < 16; ++i) {
    const int r = i * 4 + rb;
    tile[r][cc] = f2b(src[(size_t)(r0 + r) * C + c0 + cc]);
  }
  __syncthreads();
#pragma unroll
  for (int i = 0; i < 16; ++i) {
    const int r = i * 4 + rb;
    dst[(size_t)(c0 + r) * R + r0 + cc] = tile[cc][r];
  }
}

// ------------- MoE MFMA GEMM, 128x128 tile, BK=64, 4 waves (2x2) -----------
// Dense block map; XOR-swizzled LDS (reverted from 128x256: occupancy loss).
template <int MODE>
__global__ __launch_bounds__(256) void k_moe_mfma(
    const u16* __restrict__ Ab, const u16* __restrict__ Bb,
    const float* __restrict__ bias, const int* __restrict__ rtok,
    const int* __restrict__ ecnt, const int* __restrict__ eoff,
    const int* __restrict__ blkmap, u16* __restrict__ outp) {
  constexpr int K = (MODE == 0) ? DMODEL : DF;
  constexpr int N = (MODE == 0) ? DF : DMODEL;
  const int nb = blkmap[0];
  if ((int)blockIdx.y >= nb) return;
  const int ent = blkmap[1 + blockIdx.y];
  const int e = ent & 15;
  const int m0 = ent >> 4;
  const int cnt = ecnt[e];
  const int off = eoff[e];
  const int n0 = blockIdx.x * 128;
  const u16* Bw = Bb + (size_t)e * (size_t)K * N;  // [N][K] bf16
  __shared__ u16 As[128][64];
  __shared__ u16 Bs[128][64];
  const int t = threadIdx.x;
  const int w = t >> 6, l = t & 63;
  const int srow = w * 8 + (l >> 3);
  const int sscol = ((l & 7) ^ (l >> 3)) * 8;  // swizzled source chunk
  const u16* arow[4];
#pragma unroll
  for (int i = 0; i < 4; ++i) {
    const int r = m0 + i * 32 + srow;
    const int rr = (r < cnt) ? r : (cnt - 1);
    if (MODE == 0)
      arow[i] = Ab + (size_t)rtok[off + rr] * K + sscol;
    else
      arow[i] = Ab + ((size_t)off + rr) * K + sscol;
  }
  const u16* brow[4];
#pragma unroll
  for (int i = 0; i < 4; ++i)
    brow[i] = Bw + (size_t)(n0 + i * 32 + srow) * K + sscol;

  const int wr = w >> 1, wc = w & 1;
  const int lr = l & 15, lg = l >> 4;
  f32x4_t acc[4][4] = {};
  for (int k0 = 0; k0 < K; k0 += 64) {
#pragma unroll
    for (int i = 0; i < 4; ++i) {
      gl_lds16(arow[i] + k0, &As[i * 32 + w * 8][0]);
      gl_lds16(brow[i] + k0, &Bs[i * 32 + w * 8][0]);
    }
    __syncthreads();
#pragma unroll
    for (int kk = 0; kk < 2; ++kk) {
      const int cs = (kk * 32 + lg * 8) ^ ((lr & 7) << 3);  // swizzled read
      bf16x8_t af[4], bfr[4];
#pragma unroll
      for (int m = 0; m < 4; ++m)
        af[m] = *(const bf16x8_t*)&As[wr * 64 + m * 16 + lr][cs];
#pragma unroll
      for (int n = 0; n < 4; ++n)
        bfr[n] = *(const bf16x8_t*)&Bs[wc * 64 + n * 16 + lr][cs];
#pragma unroll
      for (int m = 0; m < 4; ++m)
#pragma unroll
        for (int n = 0; n < 4; ++n)
          acc[m][n] = __builtin_amdgcn_mfma_f32_16x16x32_bf16(
              af[m], bfr[n], acc[m][n], 0, 0, 0);
    }
    __syncthreads();
  }
#pragma unroll
  for (int m = 0; m < 4; ++m) {
    const int rl0 = wr * 64 + m * 16 + lg * 4;
#pragma unroll
    for (int n = 0; n < 4; ++n) {
      const int gc = n0 + wc * 64 + n * 16 + lr;
      const float bv = bias[e * N + gc];
#pragma unroll
      for (int j = 0; j < 4; ++j) {
        const int r = m0 + rl0 + j;
        if (r < cnt) {
          float v = acc[m][n][j] + bv;
          if (MODE == 0) v = v * 0.5f * (1.f + erff(v * 0.70710678118f));
          outp[((size_t)off + r) * N + gc] = f2b(v);
        }
      }
    }
  }
}

// -------- combine: out = LN( x2 + w0*y[s0] + w1*y[s1] ), y in bf16 ---------
__global__ __launch_bounds__(256) void k_ln2(
    const float* __restrict__ x2, const u16* __restrict__ ybuf,
    const int* __restrict__ t2s, const float* __restrict__ ewgt,
    const float* __restrict__ g, const float* __restrict__ be,
    float* __restrict__ outp) {
  const int tok = blockIdx.x;
  const int t = threadIdx.x;
  const int s0 = t2s[tok * 2], s1i = t2s[tok * 2 + 1];
  const float w0 = ewgt[tok * 2], w1 = ewgt[tok * 2 + 1];
  float2 v;
  {
    const float2 a = *(const float2*)(x2 + (size_t)tok * DMODEL + t * 2);
    const ushort2 y0 = *(const ushort2*)(ybuf + (size_t)s0 * DMODEL + t * 2);
    const ushort2 y1 = *(const ushort2*)(ybuf + (size_t)s1i * DMODEL + t * 2);
    v.x = a.x + w0 * b2f(y0.x) + w1 * b2f(y1.x);
    v.y = a.y + w0 * b2f(y0.y) + w1 * b2f(y1.y);
  }
  float sum1 = v.x + v.y, sum2 = v.x * v.x + v.y * v.y;
#pragma unroll
  for (int o = 32; o; o >>= 1) { sum1 += __shfl_down(sum1, o); sum2 += __shfl_down(sum2, o); }
  __shared__ float sm1[4], sm2[4];
  if ((t & 63) == 0) { sm1[t >> 6] = sum1; sm2[t >> 6] = sum2; }
  __syncthreads();
  sum1 = sm1[0] + sm1[1] + sm1[2] + sm1[3];
  sum2 = sm2[0] + sm2[1] + sm2[2] + sm2[3];
  const float mean = sum1 * (1.f / DMODEL);
  const float var = sum2 * (1.f / DMODEL) - mean * mean;
  const float rstd = rsqrtf(var + 1e-5f);
  float2 o;
  o.x = (v.x - mean) * rstd * g[t * 2] + be[t * 2];
  o.y = (v.y - mean) * rstd * g[t * 2 + 1] + be[t * 2 + 1];
  *(float2*)(outp + (size_t)tok * DMODEL + t * 2) = o;
}

extern "C" void kernel_launch(void* const* d_in, const int* in_sizes, int n_in,
                              void* d_out, int out_size, void* d_ws,
                              size_t ws_size, hipStream_t stream) {
  const float* x      = (const float*)d_in[0];
  const float* adj    = (const float*)d_in[1];
  const float* gc_w   = (const float*)d_in[2];
  const float* gc_b   = (const float*)d_in[3];
  const float* root   = (const float*)d_in[4];
  const float* in_w   = (const float*)d_in[5];
  const float* in_b   = (const float*)d_in[6];
  const float* out_w  = (const float*)d_in[7];
  const float* out_b  = (const float*)d_in[8];
  const float* ln1_g  = (const float*)d_in[9];
  const float* ln1_b  = (const float*)d_in[10];
  const float* ln2_g  = (const float*)d_in[11];
  const float* ln2_b  = (const float*)d_in[12];
  const float* gate_w = (const float*)d_in[13];
  const float* W1     = (const float*)d_in[14];
  const float* b1     = (const float*)d_in[15];
  const float* W2     = (const float*)d_in[16];
  const float* b2     = (const float*)d_in[17];
  float* outp = (float*)d_out;

  // ws layout (peak 112.3 MB); same as rounds 8-17.
  constexpr size_t MB = 1ull << 20;
  char* W = (char*)d_ws;
  u16*   adj_bf = (u16*)(W + 0);
  u16*   xht    = (u16*)(W + 16 * MB);
  u16*   xlt    = (u16*)(W + 24 * MB);
  u16*   axh    = (u16*)(W + 32 * MB);
  u16*   axl    = (u16*)(W + 40 * MB);
  float* x1     = (float*)(W + 48 * MB);
  u16*   x1h    = (u16*)(W + 64 * MB);
  u16*   x1l    = (u16*)(W + 72 * MB);
  u16*   qkvh   = (u16*)(W + 0);        // 24 MiB [r][1536] (V third unused)
  u16*   qkvl   = (u16*)(W + 24 * MB);  // 24 MiB
  u16*   vph    = (u16*)(W + 80 * MB);  // 8 MiB transposed V hi
  u16*   vpl    = (u16*)(W + 88 * MB);  // 8 MiB transposed V lo
  u16*   oatth  = (u16*)(W + 96 * MB);
  u16*   oattl  = (u16*)(W + 104 * MB);
  float* oproj  = (float*)(W + 0);      // 16 MiB (qkvh head dead after attn)
  float* x2     = (float*)(W + 96 * MB); // over dead oatt after oproj GEMM
  u16*   Wxb    = (u16*)(W + 80 * MB);  // over dead vp after attn
  u16*   hid    = (u16*)(W + 16 * MB);  // 64 MiB
  u16*   ybuf   = (u16*)(W + 0);        // 16 MiB (oproj dead after LN1)
  char*  misc   = W + 112 * MB;
  char*  Od     = (char*)d_out;
  u16*   gwh = (u16*)(Od + 0);
  u16*   gwl = (u16*)(Od + 512 * 1024);
  u16*   iwh = (u16*)(Od + 1 * MB);
  u16*   iwl = (u16*)(Od + 1 * MB + 1536 * 1024);
  u16*   owh = (u16*)(Od + 4 * MB);
  u16*   owl = (u16*)(Od + 4 * MB + 512 * 1024);
  u16*   x2b = (u16*)d_out;
  int*   eidx  = (int*)misc;
  float* ewgt  = (float*)(misc + 65536);
  int*   ecnt  = (int*)(misc + 131072);
  int*   eoff  = (int*)(misc + 131072 + 128);
  int*   efill = (int*)(misc + 131072 + 256);
  int*   rtok  = (int*)(misc + 131072 + 512);
  int*   t2s   = (int*)(misc + 131072 + 512 + 65536);
  int*   blkmap = (int*)(misc + 131072 + 512 + 131072);

  // conversions: adj (exact bf16), x^T hi/lo, weight splits
  k_cvt_b<<<dim3(8192), 256, 0, stream>>>(adj, adj_bf, NB * NSEQ * NSEQ / 4);
  k_cvt_t_hl<<<dim3(8, 16, 8), 256, 0, stream>>>(x, xht, xlt, NSEQ, DMODEL);
  k_cvt_hl<<<dim3(256), 256, 0, stream>>>(gc_w, gwh, gwl, DMODEL * DMODEL / 4);
  k_cvt_hl<<<dim3(768), 256, 0, stream>>>(in_w, iwh, iwl, 3 * DMODEL * DMODEL / 4);
  k_cvt_hl<<<dim3(256), 256, 0, stream>>>(out_w, owh, owl, DMODEL * DMODEL / 4);
  // A: ax = adj @ x  (2-term split MFMA, per batch) -> axh/axl
  k_gemm_sp<2, 0><<<dim3(4, 8, 8), 256, 0, stream>>>(
      adj_bf, nullptr, xht, xlt, nullptr, nullptr, nullptr, nullptr, axh, axl,
      nullptr, nullptr, NSEQ, DMODEL, (size_t)NSEQ * NSEQ,
      (size_t)DMODEL * NSEQ, (size_t)NSEQ * DMODEL);
  // B: x1 = x + ax @ gc_w^T + gc_b + root  -> x1 f32 + x1h/x1l
  k_gemm_sp<3, 1><<<dim3(4, 64, 1), 256, 0, stream>>>(
      axh, axl, gwh, gwl, gc_b, root, x, x1, x1h, x1l, nullptr, nullptr,
      DMODEL, DMODEL, 0, 0, 0);
  // C: qkv GEMM -> qkvh/qkvl (Q pre-scaled) + transposed V (vph/vpl)
  k_gemm_sp<3, 4><<<dim3(12, 64, 1), 256, 0, stream>>>(
      x1h, x1l, iwh, iwl, in_b, nullptr, nullptr, nullptr, qkvh, qkvl, vph,
      vpl, DMODEL, 3 * DMODEL, 0, 0, 0);
  // D: attention (128 q-rows/block, reg-prefetched K/V, setprio)
  k_attn<<<dim3(8, 8, 8), 256, 0, stream>>>(qkvh, qkvl, vph, vpl, oatth,
                                            oattl);
  // E: oproj = oatt @ out_w^T + out_b
  k_gemm_sp<3, 2><<<dim3(4, 64, 1), 256, 0, stream>>>(
      oatth, oattl, owh, owl, out_b, nullptr, nullptr, oproj, nullptr, nullptr,
      nullptr, nullptr, DMODEL, DMODEL, 0, 0, 0);
  // LN1 + fused gate: x2 (f32), x2b (bf16), eidx/ewgt
  k_ln_add<<<dim3(T_TOK), 256, 0, stream>>>(x1, oproj, ln1_g, ln1_b, gate_w,
                                            x2, x2b, eidx, ewgt);
  // MoE routing: count -> offsets(+blkmap) -> scatter
  k_zero<<<dim3(1), 128, 0, stream>>>((int*)(misc + 131072), 128);
  k_count<<<dim3(2 * T_TOK / 256), 256, 0, stream>>>(eidx, ecnt);
  k_offsets<<<dim3(1), 64, 0, stream>>>(ecnt, eoff, blkmap);
  k_scatter<<<dim3(T_TOK / 128), 256, 0, stream>>>(eidx, eoff, efill, rtok,
                                                   t2s);
  // MoE expert FFN (MFMA bf16, 128x128 tiles, dense block map)
  k_cvt_t<<<dim3(DF / 64, DMODEL / 64, NEXP), 256, 0, stream>>>(W1, Wxb,
                                                                DMODEL, DF);
  k_moe_mfma<0><<<dim3(DF / 128, 135, 1), 256, 0, stream>>>(
      x2b, Wxb, b1, rtok, ecnt, eoff, blkmap, hid);
  k_cvt_t<<<dim3(DMODEL / 64, DF / 64, NEXP), 256, 0, stream>>>(W2, Wxb, DF,
                                                                DMODEL);
  k_moe_mfma<1><<<dim3(DMODEL / 128, 135, 1), 256, 0, stream>>>(
      hid, Wxb, b2, rtok, ecnt, eoff, blkmap, ybuf);
  // combine + LN2 -> out
  k_ln2<<<dim3(T_TOK), 256, 0, stream>>>(x2, ybuf, t2s, ewgt, ln2_g, ln2_b,
                                         outp);
}